// Round 15
// baseline (76.871 us; speedup 1.0000x reference)
//
#include <hip/hip_runtime.h>

// Chamfer, B=4, N=M=8192 fp32 -> scalar. Round 18: occupancy 4 -> 6 blocks/CU.
// r17 post-mortem: +1.9us (73.7). mfma ~20us vs 6.9 MFMA-floor; suspects: (a) mixed-load
// clock derate (~65% -> floor ~10.6us, untouchable), (b) TLP thin -- 32KB LDS caps 4
// blocks/CU and the ds_read->4MFMA->32min3 chain isn't covered by 4 waves/SIMD.
// Single variable: CSPLIT 8->16 (512-Q split = 16KB LDS) + __launch_bounds__(256,6)
// (VGPR cap ~84 >> ~55 used, no spill risk; LDS would allow 10). Grid 2048, 6 blocks/CU,
// 24 waves/CU. wpart 4MB; reduce folds 16 partials. Payload/mapping/fold byte-identical
// -> absmax stays 0.0. Predict: total 73.7 -> ~69-71 if TLP-limited; neutral => clock-
// derate floor and roofline case next.

#define BATCH 4
#define NPTS 8192
#define CSPLIT 16                   // col-splits per (dirb, rowblock)
#define COLS_PER (NPTS / CSPLIT)    // 512 streamed Q points per block
#define NTILE (COLS_PER / 32)       // 16 Q-tiles per block
#define STAGE_BYTES (COLS_PER * 16 * 2)  // 16384 (16 bf16 slots/point)
#define RT 4                        // 32-row P tiles per wave (128 P/wave)
#define ROWS_BLK (4 * RT * 32)      // 512 P rows per block
#define RBLK (NPTS / ROWS_BLK)      // 16 row-blocks

typedef __attribute__((ext_vector_type(8))) short bf16x8;
typedef __attribute__((ext_vector_type(16))) float f32x16;

__device__ __forceinline__ float bf16rn(float v) {  // round-to-nearest-even to bf16 value
  unsigned u = __float_as_uint(v);
  u = (u + 0x7FFFu + ((u >> 16) & 1u)) & 0xFFFF0000u;
  return __uint_as_float(u);
}
__device__ __forceinline__ unsigned pk(float lo, float hi) {  // two bf16-valued f32 -> u32
  return (__float_as_uint(lo) >> 16) | (__float_as_uint(hi) & 0xFFFF0000u);
}

// 16-slot payload (identical arithmetic since r14):
//   coord d (limbs a,b): s[4d+]: [-2a,-2a,-2b,-2b]   t[4d+]: [a,b,a,b]
//   slots 12-15: s = (g_p, h_p, 1, 1), t = (1, 1, g_q, h_q)  -> dot adds |p|^2+|q|^2.

// Block: 4 waves x 4 P-tiles(32) = 512 P rows; 512 Q staged once (compute + ds_write).
// LDS slot (jt,half,q): half0 at slot jt*64+q, half1 at jt*64+32+q. Reader ds_read_b128
// at jt*1024 + lane*16 -> (q=lane&31, half=lane>>5) = the 32x32x16 A-fragment.
__global__ __launch_bounds__(256, 6) void chamfer_mfma_kernel(
    const float* __restrict__ p1, const float* __restrict__ p2,
    float* __restrict__ wpart) {
  const int bx = blockIdx.x;
  const int dirb = bx & 7;                  // XCD-aligned direction/batch
  const int rblk = (bx >> 3) & (RBLK - 1);  // 0..15 (512 P rows each)
  const int csp = bx >> 7;                  // 0..15 (512 Q cols each)
  const int dir = dirb >> 2, b = dirb & 3;
  const float* __restrict__ P = (dir ? p2 : p1) + (size_t)b * NPTS * 3;
  const float* __restrict__ Q = (dir ? p1 : p2) + (size_t)b * NPTS * 3;
  float* wp = wpart + ((size_t)dirb * CSPLIT + csp) * NPTS;  // private slice: no atomics

  const int t = threadIdx.x;
  const int lane = t & 63, wid = t >> 6;
  const int l31 = lane & 31, kh = lane >> 5;

  __shared__ uint4 sbuf[STAGE_BYTES / 16];  // 16 KB: the whole Q split
  char* cs = (char*)sbuf;

  // ---- stage Q: 2 points/thread, compute t-vec, ds_write both 16B halves ----
  {
    const int q = t & 31, jt0 = t >> 5;  // jt0 = 0..7
#pragma unroll
    for (int k = 0; k < 2; ++k) {
      const int jt = jt0 + 8 * k;
      const float* src = Q + 3 * (size_t)(csp * COLS_PER + jt * 32 + q);
      const float x = src[0], y = src[1], z = src[2];
      const float ax = bf16rn(x), bxl = bf16rn(x - ax);
      const float ay = bf16rn(y), byl = bf16rn(y - ay);
      const float az = bf16rn(z), bzl = bf16rn(z - az);
      const float sq = fmaf(x, x, fmaf(y, y, z * z));
      const float gq = bf16rn(sq), hq = bf16rn(sq - gq);
      uint4 h0, h1;
      h0.x = pk(ax, bxl); h0.y = h0.x;            // slots 0-3: (ax,bx,ax,bx)
      h0.z = pk(ay, byl); h0.w = h0.z;            // slots 4-7
      h1.x = pk(az, bzl); h1.y = h1.x;            // slots 8-11
      h1.z = 0x3F803F80u;                          // slots 12-13: (1,1)
      h1.w = pk(gq, hq);                           // slots 14-15: (gq,hq)
      sbuf[jt * 64 + q] = h0;
      sbuf[jt * 64 + 32 + q] = h1;
    }
  }

  // ---- bP fragments from raw P (each lane: its point's kh-half of the s-vec) ----
  const int rowbase = rblk * ROWS_BLK + wid * (RT * 32);  // wave owns 128 P = 4 tiles
  bf16x8 bP[RT];
#pragma unroll
  for (int m = 0; m < RT; ++m) {
    const float* src = P + 3 * (size_t)(rowbase + m * 32 + l31);
    const float x = src[0], y = src[1], z = src[2];
    const float ax = bf16rn(x), bxl = bf16rn(x - ax);
    const float ay = bf16rn(y), byl = bf16rn(y - ay);
    const float az = bf16rn(z), bzl = bf16rn(z - az);
    const float sp = fmaf(x, x, fmaf(y, y, z * z));
    const float gp = bf16rn(sp), hp = bf16rn(sp - gp);
    union { unsigned u[4]; bf16x8 v; } uu;
    uu.u[0] = kh ? pk(-2.f * az, -2.f * az) : pk(-2.f * ax, -2.f * ax);
    uu.u[1] = kh ? pk(-2.f * bzl, -2.f * bzl) : pk(-2.f * bxl, -2.f * bxl);
    uu.u[2] = kh ? pk(gp, hp) : pk(-2.f * ay, -2.f * ay);
    uu.u[3] = kh ? 0x3F803F80u : pk(-2.f * byl, -2.f * byl);
    bP[m] = uu.v;
  }

  __syncthreads();  // one barrier; loop below is barrier-free

  float acc[RT];
#pragma unroll
  for (int m = 0; m < RT; ++m) acc[m] = INFINITY;
  const f32x16 zero = {0.f, 0.f, 0.f, 0.f, 0.f, 0.f, 0.f, 0.f,
                       0.f, 0.f, 0.f, 0.f, 0.f, 0.f, 0.f, 0.f};

#pragma unroll 2
  for (int jt = 0; jt < NTILE; ++jt) {
    const bf16x8 aQ = *(const bf16x8*)(cs + jt * 1024 + lane * 16);  // linear ds_read_b128
#pragma unroll
    for (int m = 0; m < RT; ++m) {
      // D[q][p]: col = lane&31 = p (lane-local), rows = 16 q's in-reg (+kh half)
      const f32x16 d = __builtin_amdgcn_mfma_f32_32x32x16_bf16(aQ, bP[m], zero, 0, 0, 0);
      float v = fminf(fminf(d[0], d[1]), d[2]);      // v_min3_f32 tree, 8 ops/16 vals
      v = fminf(fminf(v, d[3]), d[4]);
      v = fminf(fminf(v, d[5]), d[6]);
      v = fminf(fminf(v, d[7]), d[8]);
      v = fminf(fminf(v, d[9]), d[10]);
      v = fminf(fminf(v, d[11]), d[12]);
      v = fminf(fminf(v, d[13]), d[14]);
      acc[m] = fminf(fminf(acc[m], v), d[15]);
    }
  }

  // lanes l and l^32 hold complementary q-subsets of the SAME p: one swap+min
#pragma unroll
  for (int m = 0; m < RT; ++m) {
    const float v = fminf(acc[m], __shfl_xor(acc[m], 32, 64));
    if (kh == 0) wp[rowbase + m * 32 + l31] = v;  // plain store, no RMW
  }
}

__global__ __launch_bounds__(256) void chamfer_reduce_kernel(const float* __restrict__ wpart,
                                                             float* __restrict__ out) {
  // 65536 (dirb,row) outputs; fold 16 csp partials each. 64 blocks x 256 threads x 4.
  float s = 0.f;
  const int base = blockIdx.x * 1024 + threadIdx.x;
#pragma unroll
  for (int k = 0; k < 4; ++k) {
    const int o = base + k * 256;          // o = dirb*NPTS + row
    const int dirb = o >> 13, row = o & (NPTS - 1);
    float v = INFINITY;
#pragma unroll
    for (int csp = 0; csp < CSPLIT; ++csp)
      v = fminf(v, wpart[((size_t)dirb * CSPLIT + csp) * NPTS + row]);  // coalesced
    s += v;
  }
#pragma unroll
  for (int off = 32; off > 0; off >>= 1) s += __shfl_down(s, off, 64);
  __shared__ float wsum[4];
  const int lane = threadIdx.x & 63, wid = threadIdx.x >> 6;
  if (lane == 0) wsum[wid] = s;
  __syncthreads();
  if (threadIdx.x == 0) atomicAdd(out, wsum[0] + wsum[1] + wsum[2] + wsum[3]);
}

extern "C" void kernel_launch(void* const* d_in, const int* in_sizes, int n_in,
                              void* d_out, int out_size, void* d_ws, size_t ws_size,
                              hipStream_t stream) {
  const float* p1 = (const float*)d_in[0];
  const float* p2 = (const float*)d_in[1];
  float* out = (float*)d_out;
  float* wpart = (float*)d_ws;  // 4 MB: 8 dirb x 16 csp x 8192 rows

  hipMemsetAsync(out, 0, sizeof(float), stream);
  chamfer_mfma_kernel<<<dim3(8 * RBLK * CSPLIT), dim3(256), 0, stream>>>(p1, p2, wpart);
  chamfer_reduce_kernel<<<dim3(64), dim3(256), 0, stream>>>(wpart, out);
}

// Round 16
// 75.155 us; speedup vs baseline: 1.0228x; 1.0228x over previous
//
#include <hip/hip_runtime.h>

// Chamfer, B=4, N=M=8192 fp32 -> scalar. Round 19: r17 revert + launch-tail shave.
// r18 post-mortem: 6 blocks/CU REGRESSED (+3.2us = doubled bP recompute + doubled wpart
// + 16-way reduce fold). Occupancy axis closed both directions. Direction-fusion
// analyzed and REJECTED (per-tile cross-lane butterfly ~240 instr > saved ~194 cyc on
// the underutilized matrix pipe). This round: exact r17 mfma kernel (CSPLIT=8, RT=4,
// (256,4), 32KB LDS) + two tail cuts:
//   - memset dispatch deleted: mfma block 0 writes out[0]=0 (stream-ordered pre-reduce)
//   - reduce regridded: 256 blocks, 1 row/thread, 8 coalesced loads + 7 fmin
// Predict total 76.9 -> ~70-72 (r17 - 1 dispatch gap - leaner reduce); >=73 => declare
// structural ceiling: 41us fixed fill + ~20us derated-serialized mfma + ~8us tail.

#define BATCH 4
#define NPTS 8192
#define CSPLIT 8                    // col-splits per (dirb, rowblock)
#define COLS_PER (NPTS / CSPLIT)    // 1024 streamed Q points per block
#define NTILE (COLS_PER / 32)       // 32 Q-tiles per block
#define STAGE_BYTES (COLS_PER * 16 * 2)  // 32768 (16 bf16 slots/point)
#define RT 4                        // 32-row P tiles per wave (128 P/wave)
#define ROWS_BLK (4 * RT * 32)      // 512 P rows per block
#define RBLK (NPTS / ROWS_BLK)      // 16 row-blocks

typedef __attribute__((ext_vector_type(8))) short bf16x8;
typedef __attribute__((ext_vector_type(16))) float f32x16;

__device__ __forceinline__ float bf16rn(float v) {  // round-to-nearest-even to bf16 value
  unsigned u = __float_as_uint(v);
  u = (u + 0x7FFFu + ((u >> 16) & 1u)) & 0xFFFF0000u;
  return __uint_as_float(u);
}
__device__ __forceinline__ unsigned pk(float lo, float hi) {  // two bf16-valued f32 -> u32
  return (__float_as_uint(lo) >> 16) | (__float_as_uint(hi) & 0xFFFF0000u);
}

// 16-slot payload (identical arithmetic since r14):
//   coord d (limbs a,b): s[4d+]: [-2a,-2a,-2b,-2b]   t[4d+]: [a,b,a,b]
//   slots 12-15: s = (g_p, h_p, 1, 1), t = (1, 1, g_q, h_q)  -> dot adds |p|^2+|q|^2.

// Block: 4 waves x 4 P-tiles(32) = 512 P rows; 1024 Q staged once (compute + ds_write).
// LDS slot (jt,half,q): half0 at slot jt*64+q, half1 at jt*64+32+q. Reader ds_read_b128
// at jt*1024 + lane*16 -> (q=lane&31, half=lane>>5) = the 32x32x16 A-fragment.
__global__ __launch_bounds__(256, 4) void chamfer_mfma_kernel(
    const float* __restrict__ p1, const float* __restrict__ p2,
    float* __restrict__ wpart, float* __restrict__ out) {
  const int bx = blockIdx.x;
  const int dirb = bx & 7;                  // XCD-aligned direction/batch
  const int rblk = (bx >> 3) & (RBLK - 1);  // 0..15 (512 P rows each)
  const int csp = bx >> 7;                  // 0..7 (1024 Q cols each)
  const int dir = dirb >> 2, b = dirb & 3;
  const float* __restrict__ P = (dir ? p2 : p1) + (size_t)b * NPTS * 3;
  const float* __restrict__ Q = (dir ? p1 : p2) + (size_t)b * NPTS * 3;
  float* wp = wpart + ((size_t)dirb * CSPLIT + csp) * NPTS;  // private slice: no atomics

  if (bx == 0 && threadIdx.x == 0) out[0] = 0.f;  // replaces the memset dispatch;
                                                  // stream-ordered before reduce.
  const int t = threadIdx.x;
  const int lane = t & 63, wid = t >> 6;
  const int l31 = lane & 31, kh = lane >> 5;

  __shared__ uint4 sbuf[STAGE_BYTES / 16];  // 32 KB: the whole Q split
  char* cs = (char*)sbuf;

  // ---- stage Q: 4 points/thread, compute t-vec, ds_write both 16B halves ----
  {
    const int q = t & 31, jt0 = t >> 5;  // jt0 = 0..7
#pragma unroll
    for (int k = 0; k < 4; ++k) {
      const int jt = jt0 + 8 * k;
      const float* src = Q + 3 * (size_t)(csp * COLS_PER + jt * 32 + q);
      const float x = src[0], y = src[1], z = src[2];
      const float ax = bf16rn(x), bxl = bf16rn(x - ax);
      const float ay = bf16rn(y), byl = bf16rn(y - ay);
      const float az = bf16rn(z), bzl = bf16rn(z - az);
      const float sq = fmaf(x, x, fmaf(y, y, z * z));
      const float gq = bf16rn(sq), hq = bf16rn(sq - gq);
      uint4 h0, h1;
      h0.x = pk(ax, bxl); h0.y = h0.x;            // slots 0-3: (ax,bx,ax,bx)
      h0.z = pk(ay, byl); h0.w = h0.z;            // slots 4-7
      h1.x = pk(az, bzl); h1.y = h1.x;            // slots 8-11
      h1.z = 0x3F803F80u;                          // slots 12-13: (1,1)
      h1.w = pk(gq, hq);                           // slots 14-15: (gq,hq)
      sbuf[jt * 64 + q] = h0;
      sbuf[jt * 64 + 32 + q] = h1;
    }
  }

  // ---- bP fragments from raw P (each lane: its point's kh-half of the s-vec) ----
  const int rowbase = rblk * ROWS_BLK + wid * (RT * 32);  // wave owns 128 P = 4 tiles
  bf16x8 bP[RT];
#pragma unroll
  for (int m = 0; m < RT; ++m) {
    const float* src = P + 3 * (size_t)(rowbase + m * 32 + l31);
    const float x = src[0], y = src[1], z = src[2];
    const float ax = bf16rn(x), bxl = bf16rn(x - ax);
    const float ay = bf16rn(y), byl = bf16rn(y - ay);
    const float az = bf16rn(z), bzl = bf16rn(z - az);
    const float sp = fmaf(x, x, fmaf(y, y, z * z));
    const float gp = bf16rn(sp), hp = bf16rn(sp - gp);
    union { unsigned u[4]; bf16x8 v; } uu;
    uu.u[0] = kh ? pk(-2.f * az, -2.f * az) : pk(-2.f * ax, -2.f * ax);
    uu.u[1] = kh ? pk(-2.f * bzl, -2.f * bzl) : pk(-2.f * bxl, -2.f * bxl);
    uu.u[2] = kh ? pk(gp, hp) : pk(-2.f * ay, -2.f * ay);
    uu.u[3] = kh ? 0x3F803F80u : pk(-2.f * byl, -2.f * byl);
    bP[m] = uu.v;
  }

  __syncthreads();  // one barrier; loop below is barrier-free

  float acc[RT];
#pragma unroll
  for (int m = 0; m < RT; ++m) acc[m] = INFINITY;
  const f32x16 zero = {0.f, 0.f, 0.f, 0.f, 0.f, 0.f, 0.f, 0.f,
                       0.f, 0.f, 0.f, 0.f, 0.f, 0.f, 0.f, 0.f};

#pragma unroll 2
  for (int jt = 0; jt < NTILE; ++jt) {
    const bf16x8 aQ = *(const bf16x8*)(cs + jt * 1024 + lane * 16);  // linear ds_read_b128
#pragma unroll
    for (int m = 0; m < RT; ++m) {
      // D[q][p]: col = lane&31 = p (lane-local), rows = 16 q's in-reg (+kh half)
      const f32x16 d = __builtin_amdgcn_mfma_f32_32x32x16_bf16(aQ, bP[m], zero, 0, 0, 0);
      float v = fminf(fminf(d[0], d[1]), d[2]);      // v_min3_f32 tree, 8 ops/16 vals
      v = fminf(fminf(v, d[3]), d[4]);
      v = fminf(fminf(v, d[5]), d[6]);
      v = fminf(fminf(v, d[7]), d[8]);
      v = fminf(fminf(v, d[9]), d[10]);
      v = fminf(fminf(v, d[11]), d[12]);
      v = fminf(fminf(v, d[13]), d[14]);
      acc[m] = fminf(fminf(acc[m], v), d[15]);
    }
  }

  // lanes l and l^32 hold complementary q-subsets of the SAME p: one swap+min
#pragma unroll
  for (int m = 0; m < RT; ++m) {
    const float v = fminf(acc[m], __shfl_xor(acc[m], 32, 64));
    if (kh == 0) wp[rowbase + m * 32 + l31] = v;  // plain store, no RMW
  }
}

__global__ __launch_bounds__(256) void chamfer_reduce_kernel(const float* __restrict__ wpart,
                                                             float* __restrict__ out) {
  // 65536 (dirb,row) outputs; 256 blocks x 256 threads, 1 row/thread.
  const int o = blockIdx.x * 256 + threadIdx.x;  // o = dirb*NPTS + row
  const int dirb = o >> 13, row = o & (NPTS - 1);
  float v = INFINITY;
#pragma unroll
  for (int csp = 0; csp < CSPLIT; ++csp)
    v = fminf(v, wpart[((size_t)dirb * CSPLIT + csp) * NPTS + row]);  // coalesced
  float s = v;
#pragma unroll
  for (int off = 32; off > 0; off >>= 1) s += __shfl_down(s, off, 64);
  __shared__ float wsum[4];
  const int lane = threadIdx.x & 63, wid = threadIdx.x >> 6;
  if (lane == 0) wsum[wid] = s;
  __syncthreads();
  if (threadIdx.x == 0) atomicAdd(out, wsum[0] + wsum[1] + wsum[2] + wsum[3]);
}

extern "C" void kernel_launch(void* const* d_in, const int* in_sizes, int n_in,
                              void* d_out, int out_size, void* d_ws, size_t ws_size,
                              hipStream_t stream) {
  const float* p1 = (const float*)d_in[0];
  const float* p2 = (const float*)d_in[1];
  float* out = (float*)d_out;
  float* wpart = (float*)d_ws;  // 2 MB: 8 dirb x 8 csp x 8192 rows

  chamfer_mfma_kernel<<<dim3(8 * RBLK * CSPLIT), dim3(256), 0, stream>>>(p1, p2, wpart, out);
  chamfer_reduce_kernel<<<dim3(256), dim3(256), 0, stream>>>(wpart, out);
}